// Round 1
// baseline (1650.926 us; speedup 1.0000x reference)
//
#include <hip/hip_runtime.h>
#include <hip/hip_bf16.h>

#define N_NODES 50000
#define N_EDGES 800000
#define HID 128

#define FMA4(accv, cs, wv) \
    accv.x = fmaf(cs, wv.x, accv.x); \
    accv.y = fmaf(cs, wv.y, accv.y); \
    accv.z = fmaf(cs, wv.z, accv.z); \
    accv.w = fmaf(cs, wv.w, accv.w)

// ---------------- encode: h = x @ enc_w + enc_b ----------------
__global__ __launch_bounds__(256) void encode_kernel(
    const float* __restrict__ x, const float* __restrict__ enc_w,
    const float* __restrict__ enc_b, float* __restrict__ h)
{
    int gid = blockIdx.x * 256 + threadIdx.x;
    if (gid >= N_NODES * HID) return;
    int n = gid >> 7;
    int j = gid & 127;
    const float* xr = x + (size_t)n * 5;
    float acc = enc_b[j];
#pragma unroll
    for (int k = 0; k < 5; ++k)
        acc = fmaf(xr[k], enc_w[k * HID + j], acc);
    h[gid] = acc;
}

// ---------------- zero aggr ----------------
__global__ __launch_bounds__(256) void zero_kernel(float4* __restrict__ p, int n4)
{
    int gid = blockIdx.x * 256 + threadIdx.x;
    if (gid < n4) p[gid] = make_float4(0.f, 0.f, 0.f, 0.f);
}

// ---------------- edge message MLP + atomic scatter ----------------
// combined = [h[dst], h[src], edge_attr]  (259)
// t1 = relu(combined @ mw1 + mb1); msg = t1 @ mw2 + mb2; aggr[dst] += msg
#define TILE_E 32
__global__ __launch_bounds__(256) void msg_kernel(
    const float* __restrict__ h, const int* __restrict__ ei,
    const float* __restrict__ ea,
    const float* __restrict__ mw1, const float* __restrict__ mb1,
    const float* __restrict__ mw2, const float* __restrict__ mb2,
    float* __restrict__ aggr)
{
    __shared__ float comb[TILE_E][260];   // 259 used, padded
    __shared__ float t1s[TILE_E][HID];
    __shared__ int dst_s[TILE_E];

    int tid = threadIdx.x;
    int e0 = blockIdx.x * TILE_E;

    // ---- load phase: 8 threads per edge ----
    {
        int el = tid >> 3;
        int l8 = tid & 7;
        int e = e0 + el;
        int src = ei[e];
        int dst = ei[N_EDGES + e];
        if (l8 == 0) {
            dst_s[el] = dst;
            comb[el][256] = ea[(size_t)e * 3 + 0];
            comb[el][257] = ea[(size_t)e * 3 + 1];
            comb[el][258] = ea[(size_t)e * 3 + 2];
        }
        const float* hi = h + (size_t)dst * HID;   // x_i
        const float* hj = h + (size_t)src * HID;   // x_j
        int c0 = l8 * 16;
#pragma unroll
        for (int c = 0; c < 16; c += 4) {
            *(float4*)&comb[el][c0 + c]       = *(const float4*)(hi + c0 + c);
            *(float4*)&comb[el][HID + c0 + c] = *(const float4*)(hj + c0 + c);
        }
    }
    __syncthreads();

    int jg = tid & 31;       // j group: 32 x 4 = 128
    int eg = tid >> 5;       // edge group: 8 x 4 = 32
    int j0 = jg * 4;
    int el0 = eg * 4;

    // ---- layer 1: [32,259] @ [259,128] ----
    float4 acc4[4];
    {
        float4 b1 = *(const float4*)(mb1 + j0);
#pragma unroll
        for (int i = 0; i < 4; ++i) acc4[i] = b1;
    }
    for (int k4 = 0; k4 < 256; k4 += 4) {
        float4 wk0 = *(const float4*)(mw1 + (size_t)(k4 + 0) * HID + j0);
        float4 wk1 = *(const float4*)(mw1 + (size_t)(k4 + 1) * HID + j0);
        float4 wk2 = *(const float4*)(mw1 + (size_t)(k4 + 2) * HID + j0);
        float4 wk3 = *(const float4*)(mw1 + (size_t)(k4 + 3) * HID + j0);
#pragma unroll
        for (int i = 0; i < 4; ++i) {
            float4 cv = *(const float4*)&comb[el0 + i][k4];
            FMA4(acc4[i], cv.x, wk0);
            FMA4(acc4[i], cv.y, wk1);
            FMA4(acc4[i], cv.z, wk2);
            FMA4(acc4[i], cv.w, wk3);
        }
    }
#pragma unroll
    for (int k = 256; k < 259; ++k) {
        float4 wk = *(const float4*)(mw1 + (size_t)k * HID + j0);
#pragma unroll
        for (int i = 0; i < 4; ++i) {
            float cs = comb[el0 + i][k];
            FMA4(acc4[i], cs, wk);
        }
    }
#pragma unroll
    for (int i = 0; i < 4; ++i) {
        float4 r;
        r.x = fmaxf(acc4[i].x, 0.f);
        r.y = fmaxf(acc4[i].y, 0.f);
        r.z = fmaxf(acc4[i].z, 0.f);
        r.w = fmaxf(acc4[i].w, 0.f);
        *(float4*)&t1s[el0 + i][j0] = r;
    }
    __syncthreads();

    // ---- layer 2: [32,128] @ [128,128] ----
    {
        float4 b2 = *(const float4*)(mb2 + j0);
#pragma unroll
        for (int i = 0; i < 4; ++i) acc4[i] = b2;
    }
    for (int k4 = 0; k4 < 128; k4 += 4) {
        float4 wk0 = *(const float4*)(mw2 + (size_t)(k4 + 0) * HID + j0);
        float4 wk1 = *(const float4*)(mw2 + (size_t)(k4 + 1) * HID + j0);
        float4 wk2 = *(const float4*)(mw2 + (size_t)(k4 + 2) * HID + j0);
        float4 wk3 = *(const float4*)(mw2 + (size_t)(k4 + 3) * HID + j0);
#pragma unroll
        for (int i = 0; i < 4; ++i) {
            float4 cv = *(const float4*)&t1s[el0 + i][k4];
            FMA4(acc4[i], cv.x, wk0);
            FMA4(acc4[i], cv.y, wk1);
            FMA4(acc4[i], cv.z, wk2);
            FMA4(acc4[i], cv.w, wk3);
        }
    }
#pragma unroll
    for (int i = 0; i < 4; ++i) {
        int d = dst_s[el0 + i];
        float* ap = aggr + (size_t)d * HID + j0;
        atomicAdd(ap + 0, acc4[i].x);
        atomicAdd(ap + 1, acc4[i].y);
        atomicAdd(ap + 2, acc4[i].z);
        atomicAdd(ap + 3, acc4[i].w);
    }
}

// ---------------- node update MLP + residual + decode ----------------
#define TILE_N 32
__global__ __launch_bounds__(256) void update_kernel(
    const float* __restrict__ h, const float* __restrict__ aggr,
    const float* __restrict__ uw1, const float* __restrict__ ub1,
    const float* __restrict__ uw2, const float* __restrict__ ub2,
    const float* __restrict__ dec_w, const float* __restrict__ dec_b,
    float* __restrict__ out)
{
    __shared__ float comb[TILE_N][260];   // 256 used, padded
    __shared__ float t1s[TILE_N][HID];
    __shared__ float hfs[TILE_N][132];

    int tid = threadIdx.x;
    int n0 = blockIdx.x * TILE_N;

    {
        int nl = tid >> 3;
        int l8 = tid & 7;
        int n = n0 + nl;
        if (n < N_NODES) {
            int c0 = l8 * 16;
#pragma unroll
            for (int c = 0; c < 16; c += 4) {
                *(float4*)&comb[nl][c0 + c]       = *(const float4*)(h + (size_t)n * HID + c0 + c);
                *(float4*)&comb[nl][HID + c0 + c] = *(const float4*)(aggr + (size_t)n * HID + c0 + c);
            }
        }
    }
    __syncthreads();

    int jg = tid & 31;
    int eg = tid >> 5;
    int j0 = jg * 4;
    int nl0 = eg * 4;

    // ---- layer 1: [32,256] @ [256,128] ----
    float4 acc4[4];
    {
        float4 b1 = *(const float4*)(ub1 + j0);
#pragma unroll
        for (int i = 0; i < 4; ++i) acc4[i] = b1;
    }
    for (int k4 = 0; k4 < 256; k4 += 4) {
        float4 wk0 = *(const float4*)(uw1 + (size_t)(k4 + 0) * HID + j0);
        float4 wk1 = *(const float4*)(uw1 + (size_t)(k4 + 1) * HID + j0);
        float4 wk2 = *(const float4*)(uw1 + (size_t)(k4 + 2) * HID + j0);
        float4 wk3 = *(const float4*)(uw1 + (size_t)(k4 + 3) * HID + j0);
#pragma unroll
        for (int i = 0; i < 4; ++i) {
            float4 cv = *(const float4*)&comb[nl0 + i][k4];
            FMA4(acc4[i], cv.x, wk0);
            FMA4(acc4[i], cv.y, wk1);
            FMA4(acc4[i], cv.z, wk2);
            FMA4(acc4[i], cv.w, wk3);
        }
    }
#pragma unroll
    for (int i = 0; i < 4; ++i) {
        float4 r;
        r.x = fmaxf(acc4[i].x, 0.f);
        r.y = fmaxf(acc4[i].y, 0.f);
        r.z = fmaxf(acc4[i].z, 0.f);
        r.w = fmaxf(acc4[i].w, 0.f);
        *(float4*)&t1s[nl0 + i][j0] = r;
    }
    __syncthreads();

    // ---- layer 2: [32,128] @ [128,128], + residual h ----
    {
        float4 b2 = *(const float4*)(ub2 + j0);
#pragma unroll
        for (int i = 0; i < 4; ++i) acc4[i] = b2;
    }
    for (int k4 = 0; k4 < 128; k4 += 4) {
        float4 wk0 = *(const float4*)(uw2 + (size_t)(k4 + 0) * HID + j0);
        float4 wk1 = *(const float4*)(uw2 + (size_t)(k4 + 1) * HID + j0);
        float4 wk2 = *(const float4*)(uw2 + (size_t)(k4 + 2) * HID + j0);
        float4 wk3 = *(const float4*)(uw2 + (size_t)(k4 + 3) * HID + j0);
#pragma unroll
        for (int i = 0; i < 4; ++i) {
            float4 cv = *(const float4*)&t1s[nl0 + i][k4];
            FMA4(acc4[i], cv.x, wk0);
            FMA4(acc4[i], cv.y, wk1);
            FMA4(acc4[i], cv.z, wk2);
            FMA4(acc4[i], cv.w, wk3);
        }
    }
#pragma unroll
    for (int i = 0; i < 4; ++i) {
        int n = n0 + nl0 + i;
        float4 hv = make_float4(0.f, 0.f, 0.f, 0.f);
        if (n < N_NODES) hv = *(const float4*)(h + (size_t)n * HID + j0);
        float4 r;
        r.x = hv.x + acc4[i].x;
        r.y = hv.y + acc4[i].y;
        r.z = hv.z + acc4[i].z;
        r.w = hv.w + acc4[i].w;
        *(float4*)&hfs[nl0 + i][j0] = r;
    }
    __syncthreads();

    // ---- decode: out[n] = hf @ dec_w + dec_b  (5 cols) ----
    if (tid < 160) {
        int nl = tid / 5;
        int c = tid % 5;
        int n = n0 + nl;
        if (n < N_NODES) {
            float acc = dec_b[c];
            for (int jj = 0; jj < HID; ++jj)
                acc = fmaf(hfs[nl][jj], dec_w[(size_t)jj * 5 + c], acc);
            out[(size_t)n * 5 + c] = acc;
        }
    }
}

extern "C" void kernel_launch(void* const* d_in, const int* in_sizes, int n_in,
                              void* d_out, int out_size, void* d_ws, size_t ws_size,
                              hipStream_t stream) {
    const float* x     = (const float*)d_in[0];
    const int*   ei    = (const int*)d_in[1];
    const float* ea    = (const float*)d_in[2];
    const float* enc_w = (const float*)d_in[3];
    const float* enc_b = (const float*)d_in[4];
    const float* dec_w = (const float*)d_in[5];
    const float* dec_b = (const float*)d_in[6];
    // Only layer l=3 contributes to the output (loop overwrites h_update,
    // which depends only on the never-updated h).
    const float* mw1 = (const float*)d_in[7]  + (size_t)3 * 259 * HID;
    const float* mb1 = (const float*)d_in[8]  + (size_t)3 * HID;
    const float* mw2 = (const float*)d_in[9]  + (size_t)3 * HID * HID;
    const float* mb2 = (const float*)d_in[10] + (size_t)3 * HID;
    const float* uw1 = (const float*)d_in[11] + (size_t)3 * 256 * HID;
    const float* ub1 = (const float*)d_in[12] + (size_t)3 * HID;
    const float* uw2 = (const float*)d_in[13] + (size_t)3 * HID * HID;
    const float* ub2 = (const float*)d_in[14] + (size_t)3 * HID;

    float* h    = (float*)d_ws;                       // [N_NODES, HID]
    float* aggr = h + (size_t)N_NODES * HID;          // [N_NODES, HID]
    float* out  = (float*)d_out;

    encode_kernel<<<(N_NODES * HID + 255) / 256, 256, 0, stream>>>(x, enc_w, enc_b, h);
    zero_kernel<<<(N_NODES * HID / 4 + 255) / 256, 256, 0, stream>>>((float4*)aggr, N_NODES * HID / 4);
    msg_kernel<<<N_EDGES / TILE_E, 256, 0, stream>>>(h, ei, ea, mw1, mb1, mw2, mb2, aggr);
    update_kernel<<<(N_NODES + TILE_N - 1) / TILE_N, 256, 0, stream>>>(
        h, aggr, uw1, ub1, uw2, ub2, dec_w, dec_b, out);
}

// Round 2
// 532.131 us; speedup vs baseline: 3.1025x; 3.1025x over previous
//
#include <hip/hip_runtime.h>
#include <hip/hip_bf16.h>

#define N_NODES 50000
#define N_EDGES 800000
#define HID 128

using short8  = __attribute__((ext_vector_type(8))) short;
using floatx4 = __attribute__((ext_vector_type(4))) float;

__device__ __forceinline__ float bf2f(ushort u) {
    union { uint u32; float f; } v; v.u32 = ((uint)u) << 16; return v.f;
}
__device__ __forceinline__ ushort f2bf(float f) {
    __hip_bfloat16 b = __float2bfloat16(f);
    return *reinterpret_cast<ushort*>(&b);
}

#define FMA4(accv, cs, wv) \
    accv.x = fmaf(cs, wv.x, accv.x); \
    accv.y = fmaf(cs, wv.y, accv.y); \
    accv.z = fmaf(cs, wv.z, accv.z); \
    accv.w = fmaf(cs, wv.w, accv.w)

// ---------------- encode: h_bf16 = bf16(x @ enc_w + enc_b) ----------------
__global__ __launch_bounds__(256) void encode_kernel(
    const float* __restrict__ x, const float* __restrict__ enc_w,
    const float* __restrict__ enc_b, ushort* __restrict__ hb)
{
    int gid = blockIdx.x * 256 + threadIdx.x;
    if (gid >= N_NODES * HID) return;
    int n = gid >> 7;
    int j = gid & 127;
    const float* xr = x + (size_t)n * 5;
    float acc = enc_b[j];
#pragma unroll
    for (int k = 0; k < 5; ++k)
        acc = fmaf(xr[k], enc_w[k * HID + j], acc);
    hb[gid] = f2bf(acc);
}

// ---------------- weight prep: transpose + bf16 ([N][K] layout) ----------------
__global__ __launch_bounds__(256) void wprep_kernel(
    const float* __restrict__ mw1, const float* __restrict__ mw2,
    ushort* __restrict__ mw1t, ushort* __restrict__ mw2t)
{
    int gid = blockIdx.x * 256 + threadIdx.x;
    if (gid < 128 * 256) {
        int c = gid >> 8, k = gid & 255;
        mw1t[c * 256 + k] = f2bf(mw1[(size_t)k * HID + c]);
    } else {
        int g = gid - 128 * 256;
        if (g < 128 * 128) {
            int c = g >> 7, k = g & 127;
            mw2t[c * 128 + k] = f2bf(mw2[(size_t)k * HID + c]);
        }
    }
}

// ---------------- zero aggr ----------------
__global__ __launch_bounds__(256) void zero_kernel(float4* __restrict__ p, int n4)
{
    int gid = blockIdx.x * 256 + threadIdx.x;
    if (gid < n4) p[gid] = make_float4(0.f, 0.f, 0.f, 0.f);
}

// ---------------- edge message MLP (MFMA bf16) + atomic scatter ----------------
// combined = [h[dst](128) | h[src](128)] bf16 in LDS; ea tail + bias folded into acc init.
#define ETILE 64
__global__ __launch_bounds__(256) void msg_mfma_kernel(
    const ushort* __restrict__ hb, const int* __restrict__ ei,
    const float* __restrict__ ea,
    const float* __restrict__ mw1, const float* __restrict__ mb1,
    const float* __restrict__ mb2,
    const ushort* __restrict__ mw1t, const ushort* __restrict__ mw2t,
    float* __restrict__ aggr)
{
    __shared__ __align__(16) ushort comb[ETILE][264];  // 256 used; 528B pitch = 4-bank skew
    __shared__ __align__(16) ushort t1s[ETILE][136];   // 128 used; 272B pitch = 4-bank skew
    __shared__ float ea_s[ETILE][4];
    __shared__ int dst_s[ETILE];

    int tid = threadIdx.x;
    int e0 = blockIdx.x * ETILE;

    // ---- gather phase: 4 threads per edge, 128B each ----
    {
        int el = tid >> 2, q = tid & 3;
        int e = e0 + el;
        int src = ei[e];
        int dst = ei[N_EDGES + e];
        if (q == 0) {
            dst_s[el] = dst;
            ea_s[el][0] = ea[(size_t)e * 3 + 0];
            ea_s[el][1] = ea[(size_t)e * 3 + 1];
            ea_s[el][2] = ea[(size_t)e * 3 + 2];
        }
        const ushort* srow = (q < 2) ? (hb + (size_t)dst * HID) : (hb + (size_t)src * HID);
        const uint4* gp = (const uint4*)(srow + (q & 1) * 64);
        uint4* lp = (uint4*)((char*)&comb[el][0] + (q >> 1) * 256 + (q & 1) * 128);
#pragma unroll
        for (int i = 0; i < 8; ++i) lp[i] = gp[i];
    }
    __syncthreads();

    int lane = tid & 63;
    int wid  = tid >> 6;
    int lhi  = lane >> 4;   // 0..3
    int llo  = lane & 15;
    int colbase = wid * 32;
    int col0 = colbase + llo;
    int col1 = colbase + 16 + llo;

    // ---- layer 1: acc init = bias + ea @ mw1[256:259] ----
    float b1_0 = mb1[col0], b1_1 = mb1[col1];
    float w0_0 = mw1[(size_t)256 * HID + col0], w0_1 = mw1[(size_t)256 * HID + col1];
    float w1_0 = mw1[(size_t)257 * HID + col0], w1_1 = mw1[(size_t)257 * HID + col1];
    float w2_0 = mw1[(size_t)258 * HID + col0], w2_1 = mw1[(size_t)258 * HID + col1];

    floatx4 acc[4][2];
#pragma unroll
    for (int m = 0; m < 4; ++m) {
#pragma unroll
        for (int r = 0; r < 4; ++r) {
            int row = m * 16 + lhi * 4 + r;
            float e0v = ea_s[row][0], e1v = ea_s[row][1], e2v = ea_s[row][2];
            acc[m][0][r] = b1_0 + e0v * w0_0 + e1v * w1_0 + e2v * w2_0;
            acc[m][1][r] = b1_1 + e0v * w0_1 + e1v * w1_1 + e2v * w2_1;
        }
    }

    // ---- layer 1 MFMA: [64,256] @ [256,128] ----
    const ushort* b1p0 = mw1t + (size_t)col0 * 256 + lhi * 8;
    const ushort* b1p1 = mw1t + (size_t)col1 * 256 + lhi * 8;
#pragma unroll
    for (int kk = 0; kk < 8; ++kk) {
        short8 bf0 = *(const short8*)(b1p0 + kk * 32);
        short8 bf1 = *(const short8*)(b1p1 + kk * 32);
#pragma unroll
        for (int m = 0; m < 4; ++m) {
            short8 a = *(const short8*)((const char*)comb + (size_t)(m * 16 + llo) * 528 + kk * 64 + lhi * 16);
            acc[m][0] = __builtin_amdgcn_mfma_f32_16x16x32_bf16(a, bf0, acc[m][0], 0, 0, 0);
            acc[m][1] = __builtin_amdgcn_mfma_f32_16x16x32_bf16(a, bf1, acc[m][1], 0, 0, 0);
        }
    }

    // ---- relu -> bf16 -> t1s ----
#pragma unroll
    for (int m = 0; m < 4; ++m) {
#pragma unroll
        for (int r = 0; r < 4; ++r) {
            int row = m * 16 + lhi * 4 + r;
            t1s[row][colbase + llo]      = f2bf(fmaxf(acc[m][0][r], 0.f));
            t1s[row][colbase + 16 + llo] = f2bf(fmaxf(acc[m][1][r], 0.f));
        }
    }
    __syncthreads();

    // ---- layer 2 MFMA: [64,128] @ [128,128] ----
    floatx4 acc2[4][2];
    float b2_0 = mb2[col0], b2_1 = mb2[col1];
#pragma unroll
    for (int m = 0; m < 4; ++m) {
#pragma unroll
        for (int r = 0; r < 4; ++r) {
            acc2[m][0][r] = b2_0;
            acc2[m][1][r] = b2_1;
        }
    }
    const ushort* b2p0 = mw2t + (size_t)col0 * 128 + lhi * 8;
    const ushort* b2p1 = mw2t + (size_t)col1 * 128 + lhi * 8;
#pragma unroll
    for (int kk = 0; kk < 4; ++kk) {
        short8 bf0 = *(const short8*)(b2p0 + kk * 32);
        short8 bf1 = *(const short8*)(b2p1 + kk * 32);
#pragma unroll
        for (int m = 0; m < 4; ++m) {
            short8 a = *(const short8*)((const char*)t1s + (size_t)(m * 16 + llo) * 272 + kk * 64 + lhi * 16);
            acc2[m][0] = __builtin_amdgcn_mfma_f32_16x16x32_bf16(a, bf0, acc2[m][0], 0, 0, 0);
            acc2[m][1] = __builtin_amdgcn_mfma_f32_16x16x32_bf16(a, bf1, acc2[m][1], 0, 0, 0);
        }
    }

    // ---- scatter ----
#pragma unroll
    for (int m = 0; m < 4; ++m) {
#pragma unroll
        for (int r = 0; r < 4; ++r) {
            int row = m * 16 + lhi * 4 + r;
            int d = dst_s[row];
            atomicAdd(&aggr[(size_t)d * HID + col0], acc2[m][0][r]);
            atomicAdd(&aggr[(size_t)d * HID + col1], acc2[m][1][r]);
        }
    }
}

// ---------------- node update MLP + residual + decode (fp32 VALU) ----------------
#define TILE_N 32
__global__ __launch_bounds__(256) void update_kernel(
    const ushort* __restrict__ hb, const float* __restrict__ aggr,
    const float* __restrict__ uw1, const float* __restrict__ ub1,
    const float* __restrict__ uw2, const float* __restrict__ ub2,
    const float* __restrict__ dec_w, const float* __restrict__ dec_b,
    float* __restrict__ out)
{
    __shared__ float comb[TILE_N][260];   // 256 used, padded
    __shared__ float t1s[TILE_N][HID];
    __shared__ float hfs[TILE_N][132];

    int tid = threadIdx.x;
    int n0 = blockIdx.x * TILE_N;

    {
        int nl = tid >> 3;
        int l8 = tid & 7;
        int n = n0 + nl;
        if (n < N_NODES) {
            int c0 = l8 * 16;
            const ushort* hr = hb + (size_t)n * HID + c0;
#pragma unroll
            for (int c = 0; c < 16; ++c) comb[nl][c0 + c] = bf2f(hr[c]);
            const float4* ar = (const float4*)(aggr + (size_t)n * HID + c0);
#pragma unroll
            for (int c = 0; c < 4; ++c)
                *(float4*)&comb[nl][HID + c0 + c * 4] = ar[c];
        }
    }
    __syncthreads();

    int jg = tid & 31;
    int eg = tid >> 5;
    int j0 = jg * 4;
    int nl0 = eg * 4;

    // ---- layer 1: [32,256] @ [256,128] ----
    float4 acc4[4];
    {
        float4 b1 = *(const float4*)(ub1 + j0);
#pragma unroll
        for (int i = 0; i < 4; ++i) acc4[i] = b1;
    }
    for (int k4 = 0; k4 < 256; k4 += 4) {
        float4 wk0 = *(const float4*)(uw1 + (size_t)(k4 + 0) * HID + j0);
        float4 wk1 = *(const float4*)(uw1 + (size_t)(k4 + 1) * HID + j0);
        float4 wk2 = *(const float4*)(uw1 + (size_t)(k4 + 2) * HID + j0);
        float4 wk3 = *(const float4*)(uw1 + (size_t)(k4 + 3) * HID + j0);
#pragma unroll
        for (int i = 0; i < 4; ++i) {
            float4 cv = *(const float4*)&comb[nl0 + i][k4];
            FMA4(acc4[i], cv.x, wk0);
            FMA4(acc4[i], cv.y, wk1);
            FMA4(acc4[i], cv.z, wk2);
            FMA4(acc4[i], cv.w, wk3);
        }
    }
#pragma unroll
    for (int i = 0; i < 4; ++i) {
        float4 r;
        r.x = fmaxf(acc4[i].x, 0.f);
        r.y = fmaxf(acc4[i].y, 0.f);
        r.z = fmaxf(acc4[i].z, 0.f);
        r.w = fmaxf(acc4[i].w, 0.f);
        *(float4*)&t1s[nl0 + i][j0] = r;
    }
    __syncthreads();

    // ---- layer 2: [32,128] @ [128,128], + residual h ----
    {
        float4 b2 = *(const float4*)(ub2 + j0);
#pragma unroll
        for (int i = 0; i < 4; ++i) acc4[i] = b2;
    }
    for (int k4 = 0; k4 < 128; k4 += 4) {
        float4 wk0 = *(const float4*)(uw2 + (size_t)(k4 + 0) * HID + j0);
        float4 wk1 = *(const float4*)(uw2 + (size_t)(k4 + 1) * HID + j0);
        float4 wk2 = *(const float4*)(uw2 + (size_t)(k4 + 2) * HID + j0);
        float4 wk3 = *(const float4*)(uw2 + (size_t)(k4 + 3) * HID + j0);
#pragma unroll
        for (int i = 0; i < 4; ++i) {
            float4 cv = *(const float4*)&t1s[nl0 + i][k4];
            FMA4(acc4[i], cv.x, wk0);
            FMA4(acc4[i], cv.y, wk1);
            FMA4(acc4[i], cv.z, wk2);
            FMA4(acc4[i], cv.w, wk3);
        }
    }
#pragma unroll
    for (int i = 0; i < 4; ++i) {
        int n = n0 + nl0 + i;
        float4 hv = make_float4(0.f, 0.f, 0.f, 0.f);
        if (n < N_NODES) {
            const ushort* hr = hb + (size_t)n * HID + j0;
            hv = make_float4(bf2f(hr[0]), bf2f(hr[1]), bf2f(hr[2]), bf2f(hr[3]));
        }
        float4 r;
        r.x = hv.x + acc4[i].x;
        r.y = hv.y + acc4[i].y;
        r.z = hv.z + acc4[i].z;
        r.w = hv.w + acc4[i].w;
        *(float4*)&hfs[nl0 + i][j0] = r;
    }
    __syncthreads();

    // ---- decode: out[n] = hf @ dec_w + dec_b  (5 cols) ----
    if (tid < 160) {
        int nl = tid / 5;
        int c = tid % 5;
        int n = n0 + nl;
        if (n < N_NODES) {
            float acc = dec_b[c];
            for (int jj = 0; jj < HID; ++jj)
                acc = fmaf(hfs[nl][jj], dec_w[(size_t)jj * 5 + c], acc);
            out[(size_t)n * 5 + c] = acc;
        }
    }
}

extern "C" void kernel_launch(void* const* d_in, const int* in_sizes, int n_in,
                              void* d_out, int out_size, void* d_ws, size_t ws_size,
                              hipStream_t stream) {
    const float* x     = (const float*)d_in[0];
    const int*   ei    = (const int*)d_in[1];
    const float* ea    = (const float*)d_in[2];
    const float* enc_w = (const float*)d_in[3];
    const float* enc_b = (const float*)d_in[4];
    const float* dec_w = (const float*)d_in[5];
    const float* dec_b = (const float*)d_in[6];
    // Only layer l=3 contributes (loop overwrites h_update; h never changes).
    const float* mw1 = (const float*)d_in[7]  + (size_t)3 * 259 * HID;
    const float* mb1 = (const float*)d_in[8]  + (size_t)3 * HID;
    const float* mw2 = (const float*)d_in[9]  + (size_t)3 * HID * HID;
    const float* mb2 = (const float*)d_in[10] + (size_t)3 * HID;
    const float* uw1 = (const float*)d_in[11] + (size_t)3 * 256 * HID;
    const float* ub1 = (const float*)d_in[12] + (size_t)3 * HID;
    const float* uw2 = (const float*)d_in[13] + (size_t)3 * HID * HID;
    const float* ub2 = (const float*)d_in[14] + (size_t)3 * HID;

    // ws layout: h_bf16 [N,H] (12.8MB) | aggr f32 [N,H] (25.6MB) | mw1t bf16 | mw2t bf16
    ushort* hb   = (ushort*)d_ws;
    float*  aggr = (float*)((char*)d_ws + (size_t)N_NODES * HID * 2);
    ushort* mw1t = (ushort*)((char*)aggr + (size_t)N_NODES * HID * 4);
    ushort* mw2t = mw1t + 128 * 256;
    float*  out  = (float*)d_out;

    encode_kernel<<<(N_NODES * HID + 255) / 256, 256, 0, stream>>>(x, enc_w, enc_b, hb);
    wprep_kernel<<<(128 * 256 + 128 * 128 + 255) / 256, 256, 0, stream>>>(mw1, mw2, mw1t, mw2t);
    zero_kernel<<<(N_NODES * HID / 4 + 255) / 256, 256, 0, stream>>>((float4*)aggr, N_NODES * HID / 4);
    msg_mfma_kernel<<<N_EDGES / ETILE, 256, 0, stream>>>(hb, ei, ea, mw1, mb1, mb2, mw1t, mw2t, aggr);
    update_kernel<<<(N_NODES + TILE_N - 1) / TILE_N, 256, 0, stream>>>(
        hb, aggr, uw1, ub1, uw2, ub2, dec_w, dec_b, out);
}

// Round 4
// 512.700 us; speedup vs baseline: 3.2201x; 1.0379x over previous
//
#include <hip/hip_runtime.h>
#include <hip/hip_bf16.h>

#define N_NODES 50000
#define N_EDGES 800000
#define HID 128

using short8  = __attribute__((ext_vector_type(8))) short;
using floatx4 = __attribute__((ext_vector_type(4))) float;

__device__ __forceinline__ float bf2f(ushort u) {
    union { uint u32; float f; } v; v.u32 = ((uint)u) << 16; return v.f;
}
__device__ __forceinline__ ushort f2bf(float f) {
    __hip_bfloat16 b = __float2bfloat16(f);
    return *reinterpret_cast<ushort*>(&b);
}

// ---------------- encode: h_bf16 = bf16(x @ enc_w + enc_b) ----------------
__global__ __launch_bounds__(256) void encode_kernel(
    const float* __restrict__ x, const float* __restrict__ enc_w,
    const float* __restrict__ enc_b, ushort* __restrict__ hb)
{
    int gid = blockIdx.x * 256 + threadIdx.x;
    if (gid >= N_NODES * HID) return;
    int n = gid >> 7;
    int j = gid & 127;
    const float* xr = x + (size_t)n * 5;
    float acc = enc_b[j];
#pragma unroll
    for (int k = 0; k < 5; ++k)
        acc = fmaf(xr[k], enc_w[k * HID + j], acc);
    hb[gid] = f2bf(acc);
}

// ---------------- weight prep: transpose + bf16 ([N][K] layout) ----------------
__global__ __launch_bounds__(256) void wprep_kernel(
    const float* __restrict__ mw1, const float* __restrict__ mw2,
    const float* __restrict__ uw1, const float* __restrict__ uw2,
    ushort* __restrict__ mw1t, ushort* __restrict__ mw2t,
    ushort* __restrict__ uw1t, ushort* __restrict__ uw2t)
{
    int gid = blockIdx.x * 256 + threadIdx.x;
    if (gid < 32768) {
        int c = gid >> 8, k = gid & 255;
        mw1t[c * 256 + k] = f2bf(mw1[(size_t)k * HID + c]);
    } else if (gid < 49152) {
        int g = gid - 32768, c = g >> 7, k = g & 127;
        mw2t[c * 128 + k] = f2bf(mw2[(size_t)k * HID + c]);
    } else if (gid < 81920) {
        int g = gid - 49152, c = g >> 8, k = g & 255;
        uw1t[c * 256 + k] = f2bf(uw1[(size_t)k * HID + c]);
    } else if (gid < 98304) {
        int g = gid - 81920, c = g >> 7, k = g & 127;
        uw2t[c * 128 + k] = f2bf(uw2[(size_t)k * HID + c]);
    }
}

// ---------------- zero ----------------
__global__ __launch_bounds__(256) void zero_kernel(float4* __restrict__ p, int n4)
{
    int gid = blockIdx.x * 256 + threadIdx.x;
    if (gid < n4) p[gid] = make_float4(0.f, 0.f, 0.f, 0.f);
}

// ---------------- CSR build ----------------
__global__ __launch_bounds__(256) void hist_kernel(
    const int* __restrict__ ei, uint* __restrict__ counts, uint* __restrict__ slot)
{
    int e = blockIdx.x * 256 + threadIdx.x;
    if (e < N_EDGES) slot[e] = atomicAdd(&counts[ei[N_EDGES + e]], 1u);
}

__global__ __launch_bounds__(1024) void scan_kernel(
    const uint* __restrict__ counts, uint* __restrict__ rowptr)
{
    __shared__ uint tmp[1024];
    int tid = threadIdx.x;
    int s = tid * 49;
    int e = min(s + 49, N_NODES);
    uint sum = 0;
    for (int i = s; i < e; ++i) sum += counts[i];
    tmp[tid] = sum;
    __syncthreads();
    for (int off = 1; off < 1024; off <<= 1) {
        uint t = (tid >= off) ? tmp[tid - off] : 0u;
        __syncthreads();
        tmp[tid] += t;
        __syncthreads();
    }
    uint run = tmp[tid] - sum;  // exclusive prefix of this chunk
    for (int i = s; i < e; ++i) { rowptr[i] = run; run += counts[i]; }
    if (tid == 0) rowptr[N_NODES] = N_EDGES;
}

__global__ __launch_bounds__(256) void scatter_kernel(
    const int* __restrict__ ei, const uint* __restrict__ rowptr,
    const uint* __restrict__ slot, uint* __restrict__ perm)
{
    int e = blockIdx.x * 256 + threadIdx.x;
    if (e < N_EDGES) {
        int dst = ei[N_EDGES + e];
        perm[rowptr[dst] + slot[e]] = (uint)e;
    }
}

// ---------------- edge message MLP (MFMA bf16), CSR order, segmented scatter ----
#define ETILE 64
__global__ __launch_bounds__(512) void msg_mfma_kernel(
    const ushort* __restrict__ hb, const int* __restrict__ ei,
    const float* __restrict__ ea, const uint* __restrict__ perm,
    const float* __restrict__ mw1, const float* __restrict__ mb1,
    const float* __restrict__ mb2,
    const ushort* __restrict__ mw1t, const ushort* __restrict__ mw2t,
    float* __restrict__ aggr)
{
    __shared__ __align__(16) ushort comb[ETILE][264];  // also reused as f32 [64][132] stage
    __shared__ __align__(16) ushort t1s[ETILE][136];
    __shared__ float ea_s[ETILE][4];
    __shared__ int dst_s[ETILE];

    int tid = threadIdx.x;
    int p0 = blockIdx.x * ETILE;

    // ---- gather phase: 8 threads per edge, 64B each (4 x uint4) ----
    {
        int el = tid >> 3, q = tid & 7;
        int e = (int)perm[p0 + el];
        int src = ei[e];
        int dst = ei[N_EDGES + e];
        if (q == 0) {
            dst_s[el] = dst;
            ea_s[el][0] = ea[(size_t)e * 3 + 0];
            ea_s[el][1] = ea[(size_t)e * 3 + 1];
            ea_s[el][2] = ea[(size_t)e * 3 + 2];
        }
        const ushort* srow = (q < 4) ? (hb + (size_t)dst * HID) : (hb + (size_t)src * HID);
        int qq = q & 3;
        const uint4* gp = (const uint4*)(srow + qq * 32);   // 32 ushorts = 4 x uint4
        uint4* lp = (uint4*)(&comb[el][(q < 4 ? 0 : HID) + qq * 32]);
        lp[0] = gp[0];
        lp[1] = gp[1];
        lp[2] = gp[2];
        lp[3] = gp[3];
    }
    __syncthreads();

    int lane = tid & 63;
    int wid  = tid >> 6;     // 0..7
    int cg   = wid & 3;      // column group (32 cols)
    int mg   = wid >> 2;     // row half: rows mg*32 .. mg*32+31
    int lhi  = lane >> 4;
    int llo  = lane & 15;
    int colbase = cg * 32;
    int col0 = colbase + llo;
    int col1 = colbase + 16 + llo;

    // ---- layer 1 acc init: bias + ea @ mw1[256:259] ----
    float b1_0 = mb1[col0], b1_1 = mb1[col1];
    float w0_0 = mw1[(size_t)256 * HID + col0], w0_1 = mw1[(size_t)256 * HID + col1];
    float w1_0 = mw1[(size_t)257 * HID + col0], w1_1 = mw1[(size_t)257 * HID + col1];
    float w2_0 = mw1[(size_t)258 * HID + col0], w2_1 = mw1[(size_t)258 * HID + col1];

    floatx4 acc[2][2];
#pragma unroll
    for (int lm = 0; lm < 2; ++lm) {
#pragma unroll
        for (int r = 0; r < 4; ++r) {
            int row = (mg * 2 + lm) * 16 + lhi * 4 + r;
            float e0v = ea_s[row][0], e1v = ea_s[row][1], e2v = ea_s[row][2];
            acc[lm][0][r] = b1_0 + e0v * w0_0 + e1v * w1_0 + e2v * w2_0;
            acc[lm][1][r] = b1_1 + e0v * w0_1 + e1v * w1_1 + e2v * w2_1;
        }
    }

    // ---- layer 1 MFMA: [64,256] @ [256,128] ----
    const ushort* b1p0 = mw1t + (size_t)col0 * 256 + lhi * 8;
    const ushort* b1p1 = mw1t + (size_t)col1 * 256 + lhi * 8;
#pragma unroll
    for (int kk = 0; kk < 8; ++kk) {
        short8 bf0 = *(const short8*)(b1p0 + kk * 32);
        short8 bf1 = *(const short8*)(b1p1 + kk * 32);
#pragma unroll
        for (int lm = 0; lm < 2; ++lm) {
            int row = (mg * 2 + lm) * 16 + llo;
            short8 a = *(const short8*)((const char*)comb + (size_t)row * 528 + kk * 64 + lhi * 16);
            acc[lm][0] = __builtin_amdgcn_mfma_f32_16x16x32_bf16(a, bf0, acc[lm][0], 0, 0, 0);
            acc[lm][1] = __builtin_amdgcn_mfma_f32_16x16x32_bf16(a, bf1, acc[lm][1], 0, 0, 0);
        }
    }

    // ---- relu -> bf16 -> t1s ----
#pragma unroll
    for (int lm = 0; lm < 2; ++lm) {
#pragma unroll
        for (int r = 0; r < 4; ++r) {
            int row = (mg * 2 + lm) * 16 + lhi * 4 + r;
            t1s[row][colbase + llo]      = f2bf(fmaxf(acc[lm][0][r], 0.f));
            t1s[row][colbase + 16 + llo] = f2bf(fmaxf(acc[lm][1][r], 0.f));
        }
    }
    __syncthreads();   // comb reads done; t1s ready

    // ---- layer 2 MFMA: [64,128] @ [128,128] ----
    floatx4 acc2[2][2];
    float b2_0 = mb2[col0], b2_1 = mb2[col1];
#pragma unroll
    for (int lm = 0; lm < 2; ++lm)
#pragma unroll
        for (int r = 0; r < 4; ++r) {
            acc2[lm][0][r] = b2_0;
            acc2[lm][1][r] = b2_1;
        }
    const ushort* b2p0 = mw2t + (size_t)col0 * 128 + lhi * 8;
    const ushort* b2p1 = mw2t + (size_t)col1 * 128 + lhi * 8;
#pragma unroll
    for (int kk = 0; kk < 4; ++kk) {
        short8 bf0 = *(const short8*)(b2p0 + kk * 32);
        short8 bf1 = *(const short8*)(b2p1 + kk * 32);
#pragma unroll
        for (int lm = 0; lm < 2; ++lm) {
            int row = (mg * 2 + lm) * 16 + llo;
            short8 a = *(const short8*)((const char*)t1s + (size_t)row * 272 + kk * 64 + lhi * 16);
            acc2[lm][0] = __builtin_amdgcn_mfma_f32_16x16x32_bf16(a, bf0, acc2[lm][0], 0, 0, 0);
            acc2[lm][1] = __builtin_amdgcn_mfma_f32_16x16x32_bf16(a, bf1, acc2[lm][1], 0, 0, 0);
        }
    }

    // ---- stage f32 messages into LDS (reuse comb memory) ----
    float (*ustage)[132] = (float(*)[132])comb;
#pragma unroll
    for (int lm = 0; lm < 2; ++lm)
#pragma unroll
        for (int r = 0; r < 4; ++r) {
            int row = (mg * 2 + lm) * 16 + lhi * 4 + r;
            ustage[row][col0] = acc2[lm][0][r];
            ustage[row][col1] = acc2[lm][1][r];
        }
    __syncthreads();

    // ---- segmented reduction over dst runs (CSR-sorted) + atomic scatter ----
    {
        int col = tid & 127;
        int rg = tid >> 7;      // 0..3, 16 rows each
        int r0 = rg * 16;
        float run = ustage[r0][col];
        int prev = dst_s[r0];
#pragma unroll 15
        for (int r = 1; r < 16; ++r) {
            int d = dst_s[r0 + r];
            float v = ustage[r0 + r][col];
            if (d != prev) {
                atomicAdd(&aggr[(size_t)prev * HID + col], run);
                run = v;
                prev = d;
            } else {
                run += v;
            }
        }
        atomicAdd(&aggr[(size_t)prev * HID + col], run);
    }
}

// ---------------- node update MLP (MFMA) + residual + decode ----------------
__global__ __launch_bounds__(512) void upd_mfma_kernel(
    const ushort* __restrict__ hb, const float* __restrict__ aggr,
    const float* __restrict__ ub1, const float* __restrict__ ub2,
    const ushort* __restrict__ uw1t, const ushort* __restrict__ uw2t,
    const float* __restrict__ dec_w, const float* __restrict__ dec_b,
    float* __restrict__ out)
{
    __shared__ __align__(16) ushort comb[64][264];
    __shared__ __align__(16) ushort t1s[64][136];

    int tid = threadIdx.x;
    int n0 = blockIdx.x * 64;

    // ---- load phase: h | bf16(aggr) ----
    {
        int nl = tid >> 3, q = tid & 7;
        int n = n0 + nl;
        if (n < N_NODES) {
            const uint4* gp = (const uint4*)(hb + (size_t)n * HID + q * 16);
            uint4* lp = (uint4*)(&comb[nl][q * 16]);
            lp[0] = gp[0];
            lp[1] = gp[1];
            const float4* ap = (const float4*)(aggr + (size_t)n * HID + q * 16);
            ushort* cp = &comb[nl][HID + q * 16];
#pragma unroll
            for (int i = 0; i < 4; ++i) {
                float4 v = ap[i];
                cp[i * 4 + 0] = f2bf(v.x);
                cp[i * 4 + 1] = f2bf(v.y);
                cp[i * 4 + 2] = f2bf(v.z);
                cp[i * 4 + 3] = f2bf(v.w);
            }
        } else {
            uint4 z = make_uint4(0, 0, 0, 0);
            uint4* lp = (uint4*)(&comb[nl][q * 16]);
            lp[0] = z; lp[1] = z;
            uint4* lp2 = (uint4*)(&comb[nl][HID + q * 16]);
            lp2[0] = z; lp2[1] = z;
        }
    }
    __syncthreads();

    int lane = tid & 63;
    int wid  = tid >> 6;
    int cg   = wid & 3;
    int mg   = wid >> 2;
    int lhi  = lane >> 4;
    int llo  = lane & 15;
    int colbase = cg * 32;
    int col0 = colbase + llo;
    int col1 = colbase + 16 + llo;

    // ---- layer 1 MFMA: [64,256] @ [256,128] ----
    floatx4 acc[2][2];
    float b1_0 = ub1[col0], b1_1 = ub1[col1];
#pragma unroll
    for (int lm = 0; lm < 2; ++lm)
#pragma unroll
        for (int r = 0; r < 4; ++r) {
            acc[lm][0][r] = b1_0;
            acc[lm][1][r] = b1_1;
        }
    const ushort* b1p0 = uw1t + (size_t)col0 * 256 + lhi * 8;
    const ushort* b1p1 = uw1t + (size_t)col1 * 256 + lhi * 8;
#pragma unroll
    for (int kk = 0; kk < 8; ++kk) {
        short8 bf0 = *(const short8*)(b1p0 + kk * 32);
        short8 bf1 = *(const short8*)(b1p1 + kk * 32);
#pragma unroll
        for (int lm = 0; lm < 2; ++lm) {
            int row = (mg * 2 + lm) * 16 + llo;
            short8 a = *(const short8*)((const char*)comb + (size_t)row * 528 + kk * 64 + lhi * 16);
            acc[lm][0] = __builtin_amdgcn_mfma_f32_16x16x32_bf16(a, bf0, acc[lm][0], 0, 0, 0);
            acc[lm][1] = __builtin_amdgcn_mfma_f32_16x16x32_bf16(a, bf1, acc[lm][1], 0, 0, 0);
        }
    }
#pragma unroll
    for (int lm = 0; lm < 2; ++lm)
#pragma unroll
        for (int r = 0; r < 4; ++r) {
            int row = (mg * 2 + lm) * 16 + lhi * 4 + r;
            t1s[row][colbase + llo]      = f2bf(fmaxf(acc[lm][0][r], 0.f));
            t1s[row][colbase + 16 + llo] = f2bf(fmaxf(acc[lm][1][r], 0.f));
        }
    __syncthreads();

    // ---- layer 2 MFMA: [64,128] @ [128,128] ----
    floatx4 acc2[2][2];
    float b2_0 = ub2[col0], b2_1 = ub2[col1];
#pragma unroll
    for (int lm = 0; lm < 2; ++lm)
#pragma unroll
        for (int r = 0; r < 4; ++r) {
            acc2[lm][0][r] = b2_0;
            acc2[lm][1][r] = b2_1;
        }
    const ushort* b2p0 = uw2t + (size_t)col0 * 128 + lhi * 8;
    const ushort* b2p1 = uw2t + (size_t)col1 * 128 + lhi * 8;
#pragma unroll
    for (int kk = 0; kk < 4; ++kk) {
        short8 bf0 = *(const short8*)(b2p0 + kk * 32);
        short8 bf1 = *(const short8*)(b2p1 + kk * 32);
#pragma unroll
        for (int lm = 0; lm < 2; ++lm) {
            int row = (mg * 2 + lm) * 16 + llo;
            short8 a = *(const short8*)((const char*)t1s + (size_t)row * 272 + kk * 64 + lhi * 16);
            acc2[lm][0] = __builtin_amdgcn_mfma_f32_16x16x32_bf16(a, bf0, acc2[lm][0], 0, 0, 0);
            acc2[lm][1] = __builtin_amdgcn_mfma_f32_16x16x32_bf16(a, bf1, acc2[lm][1], 0, 0, 0);
        }
    }
    __syncthreads();   // all t1s reads done

    // ---- hf = h + upd2 -> t1s (bf16) ----
#pragma unroll
    for (int lm = 0; lm < 2; ++lm)
#pragma unroll
        for (int r = 0; r < 4; ++r) {
            int row = (mg * 2 + lm) * 16 + lhi * 4 + r;
            float h0 = bf2f(comb[row][col0]);
            float h1 = bf2f(comb[row][col1]);
            t1s[row][col0] = f2bf(h0 + acc2[lm][0][r]);
            t1s[row][col1] = f2bf(h1 + acc2[lm][1][r]);
        }
    __syncthreads();

    // ---- decode: out[n] = hf @ dec_w + dec_b ----
    if (tid < 320) {
        int nl = tid / 5;
        int c = tid % 5;
        int n = n0 + nl;
        if (n < N_NODES) {
            float acc0 = dec_b[c];
            for (int j = 0; j < HID; ++j)
                acc0 = fmaf(bf2f(t1s[nl][j]), dec_w[(size_t)j * 5 + c], acc0);
            out[(size_t)n * 5 + c] = acc0;
        }
    }
}

extern "C" void kernel_launch(void* const* d_in, const int* in_sizes, int n_in,
                              void* d_out, int out_size, void* d_ws, size_t ws_size,
                              hipStream_t stream) {
    const float* x     = (const float*)d_in[0];
    const int*   ei    = (const int*)d_in[1];
    const float* ea    = (const float*)d_in[2];
    const float* enc_w = (const float*)d_in[3];
    const float* enc_b = (const float*)d_in[4];
    const float* dec_w = (const float*)d_in[5];
    const float* dec_b = (const float*)d_in[6];
    // Only layer l=3 contributes (loop overwrites h_update; h never changes).
    const float* mw1 = (const float*)d_in[7]  + (size_t)3 * 259 * HID;
    const float* mb1 = (const float*)d_in[8]  + (size_t)3 * HID;
    const float* mw2 = (const float*)d_in[9]  + (size_t)3 * HID * HID;
    const float* mb2 = (const float*)d_in[10] + (size_t)3 * HID;
    const float* uw1 = (const float*)d_in[11] + (size_t)3 * 256 * HID;
    const float* ub1 = (const float*)d_in[12] + (size_t)3 * HID;
    const float* uw2 = (const float*)d_in[13] + (size_t)3 * HID * HID;
    const float* ub2 = (const float*)d_in[14] + (size_t)3 * HID;

    char* w = (char*)d_ws;
    ushort* hb    = (ushort*)w;                 w += (size_t)N_NODES * HID * 2;   // 12.8MB
    float*  aggr  = (float*)w;                  w += (size_t)N_NODES * HID * 4;   // 25.6MB
    uint*   slot  = (uint*)w;                   w += (size_t)N_EDGES * 4;         // 3.2MB
    uint*   counts= (uint*)w;                   w += (size_t)50016 * 4;
    uint*   rowptr= (uint*)w;                   w += (size_t)50016 * 4;
    uint*   perm  = (uint*)w;                   w += (size_t)N_EDGES * 4;         // 3.2MB
    ushort* mw1t  = (ushort*)w;                 w += (size_t)128 * 256 * 2;
    ushort* mw2t  = (ushort*)w;                 w += (size_t)128 * 128 * 2;
    ushort* uw1t  = (ushort*)w;                 w += (size_t)128 * 256 * 2;
    ushort* uw2t  = (ushort*)w;                 w += (size_t)128 * 128 * 2;
    float*  out   = (float*)d_out;

    encode_kernel<<<(N_NODES * HID + 255) / 256, 256, 0, stream>>>(x, enc_w, enc_b, hb);
    wprep_kernel<<<(98304 + 255) / 256, 256, 0, stream>>>(mw1, mw2, uw1, uw2, mw1t, mw2t, uw1t, uw2t);
    zero_kernel<<<(N_NODES * HID / 4 + 255) / 256, 256, 0, stream>>>((float4*)aggr, N_NODES * HID / 4);
    zero_kernel<<<(12500 + 255) / 256, 256, 0, stream>>>((float4*)counts, 12500);
    hist_kernel<<<(N_EDGES + 255) / 256, 256, 0, stream>>>(ei, counts, slot);
    scan_kernel<<<1, 1024, 0, stream>>>(counts, rowptr);
    scatter_kernel<<<(N_EDGES + 255) / 256, 256, 0, stream>>>(ei, rowptr, slot, perm);
    msg_mfma_kernel<<<N_EDGES / ETILE, 512, 0, stream>>>(
        hb, ei, ea, perm, mw1, mb1, mb2, mw1t, mw2t, aggr);
    upd_mfma_kernel<<<(N_NODES + 63) / 64, 512, 0, stream>>>(
        hb, aggr, ub1, ub2, uw1t, uw2t, dec_w, dec_b, out);
}

// Round 6
// 347.320 us; speedup vs baseline: 4.7533x; 1.4762x over previous
//
#include <hip/hip_runtime.h>
#include <hip/hip_bf16.h>

#define N_NODES 50000
#define N_EDGES 800000
#define HID 128

using short8  = __attribute__((ext_vector_type(8))) short;
using floatx4 = __attribute__((ext_vector_type(4))) float;

__device__ __forceinline__ float bf2f(ushort u) {
    union { uint u32; float f; } v; v.u32 = ((uint)u) << 16; return v.f;
}
__device__ __forceinline__ ushort f2bf(float f) {
    __hip_bfloat16 b = __float2bfloat16(f);
    return *reinterpret_cast<ushort*>(&b);
}

// ---------------- weight prep: transpose + bf16 ([col][k] layout) + tailpack ----
__global__ __launch_bounds__(256) void wprep_kernel(
    const float* __restrict__ mw1, const float* __restrict__ mb1,
    const float* __restrict__ mw2,
    const float* __restrict__ uw1, const float* __restrict__ uw2,
    ushort* __restrict__ w1at, ushort* __restrict__ w1bt,
    ushort* __restrict__ w2t,
    ushort* __restrict__ uw1t, ushort* __restrict__ uw2t,
    float4* __restrict__ tailpack)
{
    int gid = blockIdx.x * 256 + threadIdx.x;
    if (gid < 16384) {
        int c = gid >> 7, k = gid & 127;
        w1at[c * 128 + k] = f2bf(mw1[(size_t)k * HID + c]);
    } else if (gid < 32768) {
        int g = gid - 16384, c = g >> 7, k = g & 127;
        w1bt[c * 128 + k] = f2bf(mw1[(size_t)(128 + k) * HID + c]);
    } else if (gid < 49152) {
        int g = gid - 32768, c = g >> 7, k = g & 127;
        w2t[c * 128 + k] = f2bf(mw2[(size_t)k * HID + c]);
    } else if (gid < 81920) {
        int g = gid - 49152, c = g >> 8, k = g & 255;
        uw1t[c * 256 + k] = f2bf(uw1[(size_t)k * HID + c]);
    } else if (gid < 98304) {
        int g = gid - 81920, c = g >> 7, k = g & 127;
        uw2t[c * 128 + k] = f2bf(uw2[(size_t)k * HID + c]);
    } else if (gid < 98432) {
        int c = gid - 98304;
        tailpack[c] = make_float4(mw1[(size_t)256 * HID + c],
                                  mw1[(size_t)257 * HID + c],
                                  mw1[(size_t)258 * HID + c],
                                  mb1[c]);
    }
}

// ---------------- zero ----------------
__global__ __launch_bounds__(256) void zero_kernel(float4* __restrict__ p, int n4)
{
    int gid = blockIdx.x * 256 + threadIdx.x;
    if (gid < n4) p[gid] = make_float4(0.f, 0.f, 0.f, 0.f);
}

// ---------------- CSR build ----------------
__global__ __launch_bounds__(256) void hist_kernel(
    const int* __restrict__ ei, uint* __restrict__ counts, uint* __restrict__ slot)
{
    int e = blockIdx.x * 256 + threadIdx.x;
    if (e < N_EDGES) slot[e] = atomicAdd(&counts[ei[N_EDGES + e]], 1u);
}

__global__ __launch_bounds__(1024) void scan_kernel(
    const uint* __restrict__ counts, uint* __restrict__ rowptr)
{
    __shared__ uint tmp[1024];
    int tid = threadIdx.x;
    int s = tid * 49;
    int e = min(s + 49, N_NODES);
    uint sum = 0;
    for (int i = s; i < e; ++i) sum += counts[i];
    tmp[tid] = sum;
    __syncthreads();
    for (int off = 1; off < 1024; off <<= 1) {
        uint t = (tid >= off) ? tmp[tid - off] : 0u;
        __syncthreads();
        tmp[tid] += t;
        __syncthreads();
    }
    uint run = tmp[tid] - sum;
    for (int i = s; i < e; ++i) { rowptr[i] = run; run += counts[i]; }
    if (tid == 0) rowptr[N_NODES] = N_EDGES;
}

__global__ __launch_bounds__(256) void scatter_kernel(
    const int* __restrict__ ei, const uint* __restrict__ rowptr,
    const uint* __restrict__ slot, uint* __restrict__ perm)
{
    int e = blockIdx.x * 256 + threadIdx.x;
    if (e < N_EDGES) {
        int dst = ei[N_EDGES + e];
        perm[rowptr[dst] + slot[e]] = (uint)e;
    }
}

// ---------------- pre: h = x@enc_w+enc_b (bf16); A = h@W1a; B = h@W1b ----------
__global__ __launch_bounds__(512, 2) void pre_kernel(
    const float* __restrict__ x, const float* __restrict__ enc_w,
    const float* __restrict__ enc_b,
    const ushort* __restrict__ w1at, const ushort* __restrict__ w1bt,
    ushort* __restrict__ hb, ushort* __restrict__ Abuf, ushort* __restrict__ Bbuf)
{
    __shared__ __align__(16) ushort htile[64][152];    // pitch 304B (76 dw, %32=12)
    __shared__ __align__(16) ushort ABst[64][280];     // pitch 560B (140 dw, %32=12)
    __shared__ float x_s[64][6];
    __shared__ float encw_s[640];
    __shared__ float encb_s[128];

    int tid = threadIdx.x;
    int n0 = blockIdx.x * 64;

    if (tid < 320) {
        int nl = tid / 5, k = tid % 5;
        int n = n0 + nl;
        x_s[nl][k] = (n < N_NODES) ? x[(size_t)n * 5 + k] : 0.f;
    }
    if (tid < 128) encb_s[tid] = enc_b[tid];
    // enc_w has 640 elements; block has 512 threads -> grid-stride
    encw_s[tid] = enc_w[tid];
    if (tid < 128) encw_s[512 + tid] = enc_w[512 + tid];
    __syncthreads();

    // ---- h compute ----
    {
        int el = tid >> 3, q = tid & 7;
        int c0 = q * 16;
        union { ushort u[16]; uint4 v[2]; } hv;
#pragma unroll
        for (int c = 0; c < 16; ++c) {
            int j = c0 + c;
            float acc = encb_s[j];
#pragma unroll
            for (int k = 0; k < 5; ++k)
                acc = fmaf(x_s[el][k], encw_s[k * 128 + j], acc);
            hv.u[c] = f2bf(acc);
        }
        *(uint4*)&htile[el][c0]     = hv.v[0];
        *(uint4*)&htile[el][c0 + 8] = hv.v[1];
        int n = n0 + el;
        if (n < N_NODES) {
            uint4* gp = (uint4*)(hb + (size_t)n * HID + c0);
            gp[0] = hv.v[0];
            gp[1] = hv.v[1];
        }
    }
    __syncthreads();

    int lane = tid & 63;
    int wid  = tid >> 6;
    int cg   = wid & 3;
    int mg   = wid >> 2;
    int lhi  = lane >> 4;
    int llo  = lane & 15;
    int col0 = cg * 32 + llo;
    int col1 = cg * 32 + 16 + llo;

    // ---- GEMM A = h @ W1a ----
    {
        floatx4 acc[2][2];
#pragma unroll
        for (int lm = 0; lm < 2; ++lm)
#pragma unroll
            for (int r = 0; r < 4; ++r) { acc[lm][0][r] = 0.f; acc[lm][1][r] = 0.f; }
        const ushort* bp0 = w1at + (size_t)col0 * 128 + lhi * 8;
        const ushort* bp1 = w1at + (size_t)col1 * 128 + lhi * 8;
#pragma unroll
        for (int kk = 0; kk < 4; ++kk) {
            short8 bf0 = *(const short8*)(bp0 + kk * 32);
            short8 bf1 = *(const short8*)(bp1 + kk * 32);
#pragma unroll
            for (int lm = 0; lm < 2; ++lm) {
                int row = (mg * 2 + lm) * 16 + llo;
                short8 a = *(const short8*)((const char*)htile + (size_t)row * 304 + kk * 64 + lhi * 16);
                acc[lm][0] = __builtin_amdgcn_mfma_f32_16x16x32_bf16(a, bf0, acc[lm][0], 0, 0, 0);
                acc[lm][1] = __builtin_amdgcn_mfma_f32_16x16x32_bf16(a, bf1, acc[lm][1], 0, 0, 0);
            }
        }
#pragma unroll
        for (int lm = 0; lm < 2; ++lm)
#pragma unroll
            for (int r = 0; r < 4; ++r) {
                int row = (mg * 2 + lm) * 16 + lhi * 4 + r;
                ABst[row][col0] = f2bf(acc[lm][0][r]);
                ABst[row][col1] = f2bf(acc[lm][1][r]);
            }
    }
    // ---- GEMM B = h @ W1b ----
    {
        floatx4 acc[2][2];
#pragma unroll
        for (int lm = 0; lm < 2; ++lm)
#pragma unroll
            for (int r = 0; r < 4; ++r) { acc[lm][0][r] = 0.f; acc[lm][1][r] = 0.f; }
        const ushort* bp0 = w1bt + (size_t)col0 * 128 + lhi * 8;
        const ushort* bp1 = w1bt + (size_t)col1 * 128 + lhi * 8;
#pragma unroll
        for (int kk = 0; kk < 4; ++kk) {
            short8 bf0 = *(const short8*)(bp0 + kk * 32);
            short8 bf1 = *(const short8*)(bp1 + kk * 32);
#pragma unroll
            for (int lm = 0; lm < 2; ++lm) {
                int row = (mg * 2 + lm) * 16 + llo;
                short8 a = *(const short8*)((const char*)htile + (size_t)row * 304 + kk * 64 + lhi * 16);
                acc[lm][0] = __builtin_amdgcn_mfma_f32_16x16x32_bf16(a, bf0, acc[lm][0], 0, 0, 0);
                acc[lm][1] = __builtin_amdgcn_mfma_f32_16x16x32_bf16(a, bf1, acc[lm][1], 0, 0, 0);
            }
        }
#pragma unroll
        for (int lm = 0; lm < 2; ++lm)
#pragma unroll
            for (int r = 0; r < 4; ++r) {
                int row = (mg * 2 + lm) * 16 + lhi * 4 + r;
                ABst[row][128 + col0] = f2bf(acc[lm][0][r]);
                ABst[row][128 + col1] = f2bf(acc[lm][1][r]);
            }
    }
    __syncthreads();

    // ---- coalesced writeout ----
    {
        int el = tid >> 3, q = tid & 7;
        int n = n0 + el;
        if (n < N_NODES) {
            uint4* ga = (uint4*)(Abuf + (size_t)n * HID + q * 16);
            ga[0] = *(uint4*)&ABst[el][q * 16];
            ga[1] = *(uint4*)&ABst[el][q * 16 + 8];
            uint4* gb = (uint4*)(Bbuf + (size_t)n * HID + q * 16);
            gb[0] = *(uint4*)&ABst[el][128 + q * 16];
            gb[1] = *(uint4*)&ABst[el][128 + q * 16 + 8];
        }
    }
}

// ---------------- edge: t1 = relu(A[dst]+B[src]+ea·tail+b1); T[dst] += t1 ------
#define ETILE 64
__global__ __launch_bounds__(512, 4) void edge_kernel(
    const ushort* __restrict__ Abuf, const ushort* __restrict__ Bbuf,
    const int* __restrict__ ei, const float* __restrict__ ea,
    const uint* __restrict__ perm, const float4* __restrict__ tailpack,
    float* __restrict__ T)
{
    __shared__ float ustage[ETILE][140];   // pitch 560B
    __shared__ __align__(16) float4 tp_s[128];
    __shared__ int dst_s[ETILE];

    int tid = threadIdx.x;
    int p0 = blockIdx.x * ETILE;

    if (tid < 128) tp_s[tid] = tailpack[tid];

    {
        int el = tid >> 3, q = tid & 7;
        int e = (int)perm[p0 + el];
        int src = ei[e];
        int dst = ei[N_EDGES + e];
        if (q == 0) dst_s[el] = dst;
        float e0 = ea[(size_t)e * 3 + 0];
        float e1 = ea[(size_t)e * 3 + 1];
        float e2 = ea[(size_t)e * 3 + 2];
        int c0 = q * 16;
        union { ushort u[16]; uint4 v[2]; } av, bv;
        const uint4* ap = (const uint4*)(Abuf + (size_t)dst * HID + c0);
        av.v[0] = ap[0]; av.v[1] = ap[1];
        const uint4* bp = (const uint4*)(Bbuf + (size_t)src * HID + c0);
        bv.v[0] = bp[0]; bv.v[1] = bp[1];
        __syncthreads();   // tp_s ready
#pragma unroll
        for (int i = 0; i < 16; ++i) {
            float4 tp = tp_s[c0 + i];
            float t = fmaf(e0, tp.x, fmaf(e1, tp.y, fmaf(e2, tp.z, tp.w)));
            t += bf2f(av.u[i]) + bf2f(bv.u[i]);
            ustage[el][c0 + i] = fmaxf(t, 0.f);
        }
    }
    __syncthreads();

    // ---- segmented reduction over dst runs + atomic scatter into T ----
    {
        int col = tid & 127;
        int rg = tid >> 7;      // 0..3, 16 rows each
        int r0 = rg * 16;
        float run = ustage[r0][col];
        int prev = dst_s[r0];
#pragma unroll 15
        for (int r = 1; r < 16; ++r) {
            int d = dst_s[r0 + r];
            float v = ustage[r0 + r][col];
            if (d != prev) {
                atomicAdd(&T[(size_t)prev * HID + col], run);
                run = v;
                prev = d;
            } else {
                run += v;
            }
        }
        atomicAdd(&T[(size_t)prev * HID + col], run);
    }
}

// ---------------- upd: aggr = T@W2 + deg*b2; node MLP + residual + decode ------
__global__ __launch_bounds__(512, 2) void upd_kernel(
    const ushort* __restrict__ hb, const float* __restrict__ T,
    const uint* __restrict__ rowptr,
    const ushort* __restrict__ w2t, const float* __restrict__ mb2,
    const float* __restrict__ ub1, const float* __restrict__ ub2,
    const ushort* __restrict__ uw1t, const ushort* __restrict__ uw2t,
    const float* __restrict__ dec_w, const float* __restrict__ dec_b,
    float* __restrict__ out)
{
    __shared__ __align__(16) ushort comb[64][280];   // [h | aggr], pitch 560B
    __shared__ __align__(16) ushort Tt[64][152];     // T bf16 / later hf, pitch 304B
    __shared__ __align__(16) ushort t1s[64][152];
    __shared__ float deg_s[64];

    int tid = threadIdx.x;
    int n0 = blockIdx.x * 64;

    // ---- load: h, bf16(T), deg ----
    {
        int el = tid >> 3, q = tid & 7;
        int n = n0 + el;
        if (n < N_NODES) {
            const uint4* gp = (const uint4*)(hb + (size_t)n * HID + q * 16);
            uint4* lp = (uint4*)&comb[el][q * 16];
            lp[0] = gp[0]; lp[1] = gp[1];
            const float4* tpp = (const float4*)(T + (size_t)n * HID + q * 16);
            union { ushort u[16]; uint4 v[2]; } tv;
#pragma unroll
            for (int i = 0; i < 4; ++i) {
                float4 v = tpp[i];
                tv.u[i * 4 + 0] = f2bf(v.x);
                tv.u[i * 4 + 1] = f2bf(v.y);
                tv.u[i * 4 + 2] = f2bf(v.z);
                tv.u[i * 4 + 3] = f2bf(v.w);
            }
            *(uint4*)&Tt[el][q * 16]     = tv.v[0];
            *(uint4*)&Tt[el][q * 16 + 8] = tv.v[1];
        } else {
            uint4 z = make_uint4(0, 0, 0, 0);
            uint4* lp = (uint4*)&comb[el][q * 16];
            lp[0] = z; lp[1] = z;
            *(uint4*)&Tt[el][q * 16]     = z;
            *(uint4*)&Tt[el][q * 16 + 8] = z;
        }
        if (tid < 64) {
            int n2 = n0 + tid;
            deg_s[tid] = (n2 < N_NODES) ? (float)(rowptr[n2 + 1] - rowptr[n2]) : 0.f;
        }
    }
    __syncthreads();

    int lane = tid & 63;
    int wid  = tid >> 6;
    int cg   = wid & 3;
    int mg   = wid >> 2;
    int lhi  = lane >> 4;
    int llo  = lane & 15;
    int col0 = cg * 32 + llo;
    int col1 = cg * 32 + 16 + llo;

    // ---- aggr = T @ W2 + deg*b2 -> comb[.,128:256] ----
    {
        floatx4 acc[2][2];
        float b0 = mb2[col0], b1 = mb2[col1];
#pragma unroll
        for (int lm = 0; lm < 2; ++lm)
#pragma unroll
            for (int r = 0; r < 4; ++r) {
                int row = (mg * 2 + lm) * 16 + lhi * 4 + r;
                acc[lm][0][r] = deg_s[row] * b0;
                acc[lm][1][r] = deg_s[row] * b1;
            }
        const ushort* bp0 = w2t + (size_t)col0 * 128 + lhi * 8;
        const ushort* bp1 = w2t + (size_t)col1 * 128 + lhi * 8;
#pragma unroll
        for (int kk = 0; kk < 4; ++kk) {
            short8 bf0 = *(const short8*)(bp0 + kk * 32);
            short8 bf1 = *(const short8*)(bp1 + kk * 32);
#pragma unroll
            for (int lm = 0; lm < 2; ++lm) {
                int row = (mg * 2 + lm) * 16 + llo;
                short8 a = *(const short8*)((const char*)Tt + (size_t)row * 304 + kk * 64 + lhi * 16);
                acc[lm][0] = __builtin_amdgcn_mfma_f32_16x16x32_bf16(a, bf0, acc[lm][0], 0, 0, 0);
                acc[lm][1] = __builtin_amdgcn_mfma_f32_16x16x32_bf16(a, bf1, acc[lm][1], 0, 0, 0);
            }
        }
#pragma unroll
        for (int lm = 0; lm < 2; ++lm)
#pragma unroll
            for (int r = 0; r < 4; ++r) {
                int row = (mg * 2 + lm) * 16 + lhi * 4 + r;
                comb[row][128 + col0] = f2bf(acc[lm][0][r]);
                comb[row][128 + col1] = f2bf(acc[lm][1][r]);
            }
    }
    __syncthreads();

    // ---- layer 1: comb @ uw1 + ub1, relu ----
    {
        floatx4 acc[2][2];
        float b0 = ub1[col0], b1 = ub1[col1];
#pragma unroll
        for (int lm = 0; lm < 2; ++lm)
#pragma unroll
            for (int r = 0; r < 4; ++r) { acc[lm][0][r] = b0; acc[lm][1][r] = b1; }
        const ushort* bp0 = uw1t + (size_t)col0 * 256 + lhi * 8;
        const ushort* bp1 = uw1t + (size_t)col1 * 256 + lhi * 8;
#pragma unroll
        for (int kk = 0; kk < 8; ++kk) {
            short8 bf0 = *(const short8*)(bp0 + kk * 32);
            short8 bf1 = *(const short8*)(bp1 + kk * 32);
#pragma unroll
            for (int lm = 0; lm < 2; ++lm) {
                int row = (mg * 2 + lm) * 16 + llo;
                short8 a = *(const short8*)((const char*)comb + (size_t)row * 560 + kk * 64 + lhi * 16);
                acc[lm][0] = __builtin_amdgcn_mfma_f32_16x16x32_bf16(a, bf0, acc[lm][0], 0, 0, 0);
                acc[lm][1] = __builtin_amdgcn_mfma_f32_16x16x32_bf16(a, bf1, acc[lm][1], 0, 0, 0);
            }
        }
#pragma unroll
        for (int lm = 0; lm < 2; ++lm)
#pragma unroll
            for (int r = 0; r < 4; ++r) {
                int row = (mg * 2 + lm) * 16 + lhi * 4 + r;
                t1s[row][col0] = f2bf(fmaxf(acc[lm][0][r], 0.f));
                t1s[row][col1] = f2bf(fmaxf(acc[lm][1][r], 0.f));
            }
    }
    __syncthreads();

    // ---- layer 2 + residual -> Tt (hf) ----
    {
        floatx4 acc[2][2];
        float b0 = ub2[col0], b1 = ub2[col1];
#pragma unroll
        for (int lm = 0; lm < 2; ++lm)
#pragma unroll
            for (int r = 0; r < 4; ++r) { acc[lm][0][r] = b0; acc[lm][1][r] = b1; }
        const ushort* bp0 = uw2t + (size_t)col0 * 128 + lhi * 8;
        const ushort* bp1 = uw2t + (size_t)col1 * 128 + lhi * 8;
#pragma unroll
        for (int kk = 0; kk < 4; ++kk) {
            short8 bf0 = *(const short8*)(bp0 + kk * 32);
            short8 bf1 = *(const short8*)(bp1 + kk * 32);
#pragma unroll
            for (int lm = 0; lm < 2; ++lm) {
                int row = (mg * 2 + lm) * 16 + llo;
                short8 a = *(const short8*)((const char*)t1s + (size_t)row * 304 + kk * 64 + lhi * 16);
                acc[lm][0] = __builtin_amdgcn_mfma_f32_16x16x32_bf16(a, bf0, acc[lm][0], 0, 0, 0);
                acc[lm][1] = __builtin_amdgcn_mfma_f32_16x16x32_bf16(a, bf1, acc[lm][1], 0, 0, 0);
            }
        }
        __syncthreads();   // Tt reads (aggr GEMM) long done; safe to overwrite
#pragma unroll
        for (int lm = 0; lm < 2; ++lm)
#pragma unroll
            for (int r = 0; r < 4; ++r) {
                int row = (mg * 2 + lm) * 16 + lhi * 4 + r;
                float h0 = bf2f(comb[row][col0]);
                float h1 = bf2f(comb[row][col1]);
                Tt[row][col0] = f2bf(h0 + acc[lm][0][r]);
                Tt[row][col1] = f2bf(h1 + acc[lm][1][r]);
            }
    }
    __syncthreads();

    // ---- decode ----
    if (tid < 320) {
        int nl = tid / 5;
        int c = tid % 5;
        int n = n0 + nl;
        if (n < N_NODES) {
            float acc0 = dec_b[c];
            for (int j = 0; j < HID; ++j)
                acc0 = fmaf(bf2f(Tt[nl][j]), dec_w[(size_t)j * 5 + c], acc0);
            out[(size_t)n * 5 + c] = acc0;
        }
    }
}

extern "C" void kernel_launch(void* const* d_in, const int* in_sizes, int n_in,
                              void* d_out, int out_size, void* d_ws, size_t ws_size,
                              hipStream_t stream) {
    const float* x     = (const float*)d_in[0];
    const int*   ei    = (const int*)d_in[1];
    const float* ea    = (const float*)d_in[2];
    const float* enc_w = (const float*)d_in[3];
    const float* enc_b = (const float*)d_in[4];
    const float* dec_w = (const float*)d_in[5];
    const float* dec_b = (const float*)d_in[6];
    // Only layer l=3 contributes (loop overwrites h_update; h never changes).
    const float* mw1 = (const float*)d_in[7]  + (size_t)3 * 259 * HID;
    const float* mb1 = (const float*)d_in[8]  + (size_t)3 * HID;
    const float* mw2 = (const float*)d_in[9]  + (size_t)3 * HID * HID;
    const float* mb2 = (const float*)d_in[10] + (size_t)3 * HID;
    const float* uw1 = (const float*)d_in[11] + (size_t)3 * 256 * HID;
    const float* ub1 = (const float*)d_in[12] + (size_t)3 * HID;
    const float* uw2 = (const float*)d_in[13] + (size_t)3 * HID * HID;
    const float* ub2 = (const float*)d_in[14] + (size_t)3 * HID;

    char* w = (char*)d_ws;
    ushort* hb    = (ushort*)w;  w += (size_t)N_NODES * HID * 2;   // 12.8MB
    ushort* Abuf  = (ushort*)w;  w += (size_t)N_NODES * HID * 2;   // 12.8MB
    ushort* Bbuf  = (ushort*)w;  w += (size_t)N_NODES * HID * 2;   // 12.8MB
    float*  T     = (float*)w;   w += (size_t)N_NODES * HID * 4;   // 25.6MB
    uint*   slot  = (uint*)w;    w += (size_t)N_EDGES * 4;         // 3.2MB
    uint*   counts= (uint*)w;    w += (size_t)50016 * 4;
    uint*   rowptr= (uint*)w;    w += (size_t)50016 * 4;
    uint*   perm  = (uint*)w;    w += (size_t)N_EDGES * 4;         // 3.2MB
    ushort* w1at  = (ushort*)w;  w += (size_t)128 * 128 * 2;
    ushort* w1bt  = (ushort*)w;  w += (size_t)128 * 128 * 2;
    ushort* w2t   = (ushort*)w;  w += (size_t)128 * 128 * 2;
    ushort* uw1t  = (ushort*)w;  w += (size_t)128 * 256 * 2;
    ushort* uw2t  = (ushort*)w;  w += (size_t)128 * 128 * 2;
    float4* tailpack = (float4*)w; w += (size_t)128 * 16;
    float*  out   = (float*)d_out;

    wprep_kernel<<<(98432 + 255) / 256, 256, 0, stream>>>(
        mw1, mb1, mw2, uw1, uw2, w1at, w1bt, w2t, uw1t, uw2t, tailpack);
    zero_kernel<<<(N_NODES * HID / 4 + 255) / 256, 256, 0, stream>>>((float4*)T, N_NODES * HID / 4);
    zero_kernel<<<(12500 + 255) / 256, 256, 0, stream>>>((float4*)counts, 12500);
    hist_kernel<<<(N_EDGES + 255) / 256, 256, 0, stream>>>(ei, counts, slot);
    scan_kernel<<<1, 1024, 0, stream>>>(counts, rowptr);
    scatter_kernel<<<(N_EDGES + 255) / 256, 256, 0, stream>>>(ei, rowptr, slot, perm);
    pre_kernel<<<(N_NODES + 63) / 64, 512, 0, stream>>>(
        x, enc_w, enc_b, w1at, w1bt, hb, Abuf, Bbuf);
    edge_kernel<<<N_EDGES / ETILE, 512, 0, stream>>>(
        Abuf, Bbuf, ei, ea, perm, tailpack, T);
    upd_kernel<<<(N_NODES + 63) / 64, 512, 0, stream>>>(
        hb, T, rowptr, w2t, mb2, ub1, ub2, uw1t, uw2t, dec_w, dec_b, out);
}